// Round 26
// baseline (117.250 us; speedup 1.0000x reference)
//
#include <hip/hip_runtime.h>
#include <math.h>

#define BATCH 64
#define NOBJ 16
#define NPRIOR 8732
#define NC 91
#define IMG 300.0f
#define GPB 1092                   // 8-row groups per batch (lse waves)
#define NGROUP (GPB * BATCH)       // 69888
#define LSE_WAVES 6144             // one-wave pipelines (1536 blocks x 4)
#define GBINS 2048                 // histogram bins: bin = min(2047, v*128)
#define MSPLIT 16                  // match blocks per batch
#define SL 546                     // priors per match slice (16*546 >= 8732)

// ---------------------------------------------------------------- k_fused
// Heterogeneous kernel: 2560 blocks, 256 thr. bid%5<2 -> match body (1024
// blocks, R25-verified); else -> lse body (1536 blocks x 4 independent
// one-wave depth-2 pipelines = k_ce's verified schedule minus the conf_t
// gather). Match (VALU-bound) and lse (memory-bound) co-schedule on the
// CUs -> the serial M1 + CE sum collapses toward max(M1, CE).
#define LSE_ISSUE(gg, R0, R1, R2, NF)                                          \
    {   int b_ = (gg) / GPB, ci_ = (gg) - b_ * GPB;                            \
        int p0_ = ci_ * 8;                                                     \
        int rows_ = min(8, NPRIOR - p0_);                                      \
        NF = (rows_ * NC) >> 2;                                                \
        const float4* s_ = (const float4*)(conf_data + ((size_t)b_ * NPRIOR + p0_) * NC); \
        R0 = s_[lane];                                                         \
        if (lane + 64  < NF) R1 = s_[lane + 64];                               \
        if (lane + 128 < NF) R2 = s_[lane + 128]; }

#define LSE_WRITE(SB, R0, R1, R2, NF)                                          \
    {   float4* d_ = (float4*)(SB);                                            \
        d_[lane] = R0;                                                         \
        if (lane + 64  < NF) d_[lane + 64]  = R1;                              \
        if (lane + 128 < NF) d_[lane + 128] = R2; }

#define LSE_COMPUTE(gg, SB)                                                    \
    {   int b_ = (gg) / GPB, ci_ = (gg) - b_ * GPB;                            \
        int p0_ = ci_ * 8;                                                     \
        int rows_ = min(8, NPRIOR - p0_);                                      \
        int rr_ = lane >> 3, q_ = lane & 7;                                    \
        if (rr_ < rows_) {                                                     \
            const float* row_ = (SB) + rr_ * NC;                               \
            float s_ = 0.0f;                                                   \
            _Pragma("unroll")                                                  \
            for (int i_ = q_; i_ < NC; i_ += 8) s_ += __expf(row_[i_]);        \
            s_ += __shfl_xor(s_, 1);                                           \
            s_ += __shfl_xor(s_, 2);                                           \
            s_ += __shfl_xor(s_, 4);                                           \
            if (q_ == 0) {                                                     \
                size_t o_ = (size_t)b_ * NPRIOR + p0_ + rr_;                   \
                lse_g[o_] = __logf(s_);                                        \
                c0_g[o_]  = row_[0];                                           \
            } } }

__global__ __launch_bounds__(256) void k_fused(
    const float* __restrict__ loc_data,
    const float* __restrict__ gt_boxes,
    const int*   __restrict__ gt_labels,
    const float* __restrict__ priors,
    const float* __restrict__ conf_data,
    int*   __restrict__ conf_t,
    float* __restrict__ ll_part,           // [B*MSPLIT]
    int*   __restrict__ np_part,           // [B*MSPLIT]
    float* __restrict__ candv,             // [B][MSPLIT][NOBJ]
    int*   __restrict__ candi,             // [B][MSPLIT][NOBJ]
    float* __restrict__ lse_g,             // [B][P]
    float* __restrict__ c0_g)              // [B][P]
{
    __shared__ float sbuf[4][2][8 * NC];   // lse path: per-wave dbuf (23.3KB)
    __shared__ float bx0[NOBJ], by0[NOBJ], bx1[NOBJ], by1[NOBJ], barea[NOBJ];
    __shared__ int   blab[NOBJ];
    __shared__ float rv[NOBJ][4];
    __shared__ int   ri[NOBJ][4];
    __shared__ float red_f[4];
    __shared__ int   red_i[4];

    const int bid  = blockIdx.x;
    const int tid  = threadIdx.x;
    const int lane = tid & 63;
    const int wv   = tid >> 6;             // 0..3
    const int r5   = bid % 5;

    if (r5 < 2) {
        // ---------------- MATCH body (R25-verified) ----------------
        const int m   = (bid / 5) * 2 + r5;     // 0..1023
        const int blk = m % MSPLIT;
        const int b   = m / MSPLIT;
        const int p0   = blk * SL;
        const int pend = min(p0 + SL, NPRIOR);

        if (tid < NOBJ) {
            float4 g = ((const float4*)gt_boxes)[(size_t)b * NOBJ + tid];
            float x0 = g.x * (1.0f / IMG), y0 = g.y * (1.0f / IMG);
            float x1 = g.z * (1.0f / IMG), y1 = g.w * (1.0f / IMG);
            bx0[tid] = x0; by0[tid] = y0; bx1[tid] = x1; by1[tid] = y1;
            barea[tid] = (x1 - x0) * (y1 - y0);
            blab[tid] = gt_labels[b * NOBJ + tid];
        }
        __syncthreads();

        float bv[NOBJ];
        int   bi[NOBJ];
#pragma unroll
        for (int j = 0; j < NOBJ; j++) { bv[j] = -1.0f; bi[j] = 0x7fffffff; }

        int np_local = 0;
        float ll_local = 0.0f;

        for (int p = p0 + tid; p < pend; p += 256) {
            float4 pr = ((const float4*)priors)[p];
            float cx = pr.x, cy = pr.y, w = pr.z, h = pr.w;
            float px0 = cx - 0.5f * w, py0 = cy - 0.5f * h;
            float px1 = cx + 0.5f * w, py1 = cy + 0.5f * h;
            float pa = w * h;
            float maxv = -1.0f; int maxj = 0;
#pragma unroll
            for (int j = 0; j < NOBJ; j++) {
                float ltx = fmaxf(bx0[j], px0), lty = fmaxf(by0[j], py0);
                float rbx = fminf(bx1[j], px1), rby = fminf(by1[j], py1);
                float iw = fmaxf(rbx - ltx, 0.0f), ih = fmaxf(rby - lty, 0.0f);
                float inter = iw * ih;
                float iou = inter / (barea[j] + pa - inter);
                if (iou > maxv) { maxv = iou; maxj = j; }
                if (iou > bv[j]) { bv[j] = iou; bi[j] = p; }
            }
            int conf = (maxv < 0.5f) ? 0 : blab[maxj];
            conf_t[(size_t)b * NPRIOR + p] = conf;
            if (conf > 0) {
                np_local++;
                float mx0 = bx0[maxj], my0 = by0[maxj];
                float mx1 = bx1[maxj], my1 = by1[maxj];
                float g0 = ((mx0 + mx1) * 0.5f - cx) / (0.1f * w);
                float g1 = ((my0 + my1) * 0.5f - cy) / (0.1f * h);
                float g2 = logf((mx1 - mx0) / w) * 5.0f;
                float g3 = logf((my1 - my0) / h) * 5.0f;
                float4 lv = ((const float4*)loc_data)[(size_t)b * NPRIOR + p];
                float d0 = lv.x - g0, d1 = lv.y - g1, d2 = lv.z - g2, d3 = lv.w - g3;
                float a0 = fabsf(d0), a1 = fabsf(d1), a2 = fabsf(d2), a3 = fabsf(d3);
                ll_local += (a0 < 1.f ? 0.5f * d0 * d0 : a0 - 0.5f)
                          + (a1 < 1.f ? 0.5f * d1 * d1 : a1 - 0.5f)
                          + (a2 < 1.f ? 0.5f * d2 * d2 : a2 - 0.5f)
                          + (a3 < 1.f ? 0.5f * d3 * d3 : a3 - 0.5f);
            }
        }

#pragma unroll
        for (int j = 0; j < NOBJ; j++) {
            float v = bv[j]; int ix = bi[j];
            for (int off = 32; off; off >>= 1) {
                float v2 = __shfl_xor(v, off);
                int   i2 = __shfl_xor(ix, off);
                if (v2 > v || (v2 == v && i2 < ix)) { v = v2; ix = i2; }
            }
            if (lane == 0) { rv[j][wv] = v; ri[j][wv] = ix; }
        }
        for (int off = 32; off; off >>= 1) {
            ll_local += __shfl_xor(ll_local, off);
            np_local += __shfl_xor(np_local, off);
        }
        if (lane == 0) { red_f[wv] = ll_local; red_i[wv] = np_local; }
        __syncthreads();
        if (tid < NOBJ) {
            int j = tid;
            float v = rv[j][0]; int ix = ri[j][0];
#pragma unroll
            for (int w2 = 1; w2 < 4; w2++) {
                float v2 = rv[j][w2]; int i2 = ri[j][w2];
                if (v2 > v || (v2 == v && i2 < ix)) { v = v2; ix = i2; }
            }
            size_t o = ((size_t)b * MSPLIT + blk) * NOBJ + j;
            candv[o] = v;
            candi[o] = ix;
        }
        if (tid == 0) {
            ll_part[b * MSPLIT + blk] = red_f[0] + red_f[1] + red_f[2] + red_f[3];
            np_part[b * MSPLIT + blk] = red_i[0] + red_i[1] + red_i[2] + red_i[3];
        }
    } else {
        // ---------------- LSE body (k_ce schedule, no conf_t) ----------------
        const int lblk = (bid / 5) * 3 + (r5 - 2);   // 0..1535
        int g = lblk * 4 + wv;                        // wave-global 0..6143
        const int G = LSE_WAVES;
        float* SB0 = &sbuf[wv][0][0];
        float* SB1 = &sbuf[wv][1][0];

        float4 a0, a1, a2, b0, b1, b2;
        int nfA = 0, nfB = 0;

        LSE_ISSUE(g, a0, a1, a2, nfA);
        if (g + G < NGROUP) LSE_ISSUE(g + G, b0, b1, b2, nfB);
        LSE_WRITE(SB0, a0, a1, a2, nfA);

        for (; g < NGROUP; g += 2 * G) {
            if (g + 2 * G < NGROUP) LSE_ISSUE(g + 2 * G, a0, a1, a2, nfA);
            LSE_COMPUTE(g, SB0);
            if (g + G < NGROUP) {
                LSE_WRITE(SB1, b0, b1, b2, nfB);
                if (g + 3 * G < NGROUP) LSE_ISSUE(g + 3 * G, b0, b1, b2, nfB);
                LSE_COMPUTE(g + G, SB1);
                if (g + 2 * G < NGROUP) LSE_WRITE(SB0, a0, a1, a2, nfA);
            }
        }
    }
}

// ---------------------------------------------------------------- k_bpi_fix
// One wave per batch: reduce MSPLIT candidate copies -> bpi, then apply the
// override to <=16 priors with EXACT ll/np deltas (R23-verified).
__global__ __launch_bounds__(64) void k_bpi_fix(
    const float* __restrict__ loc_data,
    const float* __restrict__ gt_boxes,
    const int*   __restrict__ gt_labels,
    const float* __restrict__ priors,
    const float* __restrict__ candv,
    const int*   __restrict__ candi,
    int*   __restrict__ conf_t,
    float* __restrict__ ll_fix,            // [B]
    int*   __restrict__ np_fix)            // [B]
{
    __shared__ int bpi_s[NOBJ];
    const int b = blockIdx.x;
    const int lane = threadIdx.x;

    if (lane < NOBJ) {
        size_t base = (size_t)b * MSPLIT * NOBJ + lane;
        float v = candv[base]; int ix = candi[base];
#pragma unroll
        for (int c = 1; c < MSPLIT; c++) {
            float v2 = candv[base + c * NOBJ];
            int   i2 = candi[base + c * NOBJ];
            if (v2 > v || (v2 == v && i2 < ix)) { v = v2; ix = i2; }
        }
        bpi_s[lane] = ix;
    }
    __syncthreads();

    float ll_d = 0.0f;
    int   np_d = 0;

    if (lane < NOBJ) {
        const int j = lane;
        const int ps = bpi_s[j];
        bool last = true;
        for (int j2 = j + 1; j2 < NOBJ; j2++)
            if (bpi_s[j2] == ps) last = false;
        if (last) {
            float4 pr = ((const float4*)priors)[ps];
            float cx = pr.x, cy = pr.y, w = pr.z, h = pr.w;
            float px0 = cx - 0.5f * w, py0 = cy - 0.5f * h;
            float px1 = cx + 0.5f * w, py1 = cy + 0.5f * h;
            float pa = w * h;
            float maxv = -1.0f;
            float mx0 = 0, my0 = 0, mx1 = 0, my1 = 0;
            float jx0 = 0, jy0 = 0, jx1 = 0, jy1 = 0;
            for (int j2 = 0; j2 < NOBJ; j2++) {
                float4 g = ((const float4*)gt_boxes)[(size_t)b * NOBJ + j2];
                float x0 = g.x * (1.0f / IMG), y0 = g.y * (1.0f / IMG);
                float x1 = g.z * (1.0f / IMG), y1 = g.w * (1.0f / IMG);
                float area = (x1 - x0) * (y1 - y0);
                float ltx = fmaxf(x0, px0), lty = fmaxf(y0, py0);
                float rbx = fminf(x1, px1), rby = fminf(y1, py1);
                float iw = fmaxf(rbx - ltx, 0.0f), ih = fmaxf(rby - lty, 0.0f);
                float inter = iw * ih;
                float iou = inter / (area + pa - inter);
                if (iou > maxv) { maxv = iou; mx0 = x0; my0 = y0; mx1 = x1; my1 = y1; }
                if (j2 == j)    { jx0 = x0; jy0 = y0; jx1 = x1; jy1 = y1; }
            }
            float4 lv = ((const float4*)loc_data)[(size_t)b * NPRIOR + ps];
            if (maxv >= 0.5f) {
                float g0 = ((mx0 + mx1) * 0.5f - cx) / (0.1f * w);
                float g1 = ((my0 + my1) * 0.5f - cy) / (0.1f * h);
                float g2 = logf((mx1 - mx0) / w) * 5.0f;
                float g3 = logf((my1 - my0) / h) * 5.0f;
                float d0 = lv.x - g0, d1 = lv.y - g1, d2 = lv.z - g2, d3 = lv.w - g3;
                float a0 = fabsf(d0), a1 = fabsf(d1), a2 = fabsf(d2), a3 = fabsf(d3);
                ll_d -= (a0 < 1.f ? 0.5f * d0 * d0 : a0 - 0.5f)
                      + (a1 < 1.f ? 0.5f * d1 * d1 : a1 - 0.5f)
                      + (a2 < 1.f ? 0.5f * d2 * d2 : a2 - 0.5f)
                      + (a3 < 1.f ? 0.5f * d3 * d3 : a3 - 0.5f);
                np_d -= 1;
            }
            {
                float g0 = ((jx0 + jx1) * 0.5f - cx) / (0.1f * w);
                float g1 = ((jy0 + jy1) * 0.5f - cy) / (0.1f * h);
                float g2 = logf((jx1 - jx0) / w) * 5.0f;
                float g3 = logf((jy1 - jy0) / h) * 5.0f;
                float d0 = lv.x - g0, d1 = lv.y - g1, d2 = lv.z - g2, d3 = lv.w - g3;
                float a0 = fabsf(d0), a1 = fabsf(d1), a2 = fabsf(d2), a3 = fabsf(d3);
                ll_d += (a0 < 1.f ? 0.5f * d0 * d0 : a0 - 0.5f)
                      + (a1 < 1.f ? 0.5f * d1 * d1 : a1 - 0.5f)
                      + (a2 < 1.f ? 0.5f * d2 * d2 : a2 - 0.5f)
                      + (a3 < 1.f ? 0.5f * d3 * d3 : a3 - 0.5f);
                np_d += 1;
            }
            conf_t[(size_t)b * NPRIOR + ps] = gt_labels[b * NOBJ + j];
        }
    }

    for (int off = 32; off; off >>= 1) {
        ll_d += __shfl_xor(ll_d, off);
        np_d += __shfl_xor(np_d, off);
    }
    if (lane == 0) { ll_fix[b] = ll_d; np_fix[b] = np_d; }
}

// ---------------------------------------------------------------- k_histsel2
// One block (256 thr) per batch: reconstruct mine on the fly (coalesced
// lse/c0/conf_t reads; ce = lse - c0 identical to the old path), accumulate
// pos_ce via rare gathers of conf_data[...][tgt], LDS histogram, suffix
// scan, bin-mean top-k (R16-verified). The mine array no longer exists.
__global__ __launch_bounds__(256) void k_histsel2(
    const float* __restrict__ conf_data,
    const float* __restrict__ lse_g,
    const float* __restrict__ c0_g,
    const int*   __restrict__ conf_t,
    const int*   __restrict__ np_part,
    const int*   __restrict__ np_fix,
    float* __restrict__ lc2,               // [B] topk sum
    float* __restrict__ lc3)               // [B] pos_ce sum
{
    __shared__ int   lh[GBINS];            // 8 KB
    __shared__ float ls[GBINS];            // 8 KB
    __shared__ int   wtot[4];
    __shared__ int   s_B0, s_r;
    __shared__ float red_f[4];
    __shared__ float red_p[4];

    const int b = blockIdx.x;
    const int tid = threadIdx.x;
    const int lane = tid & 63;
    const int wave = tid >> 6;

#pragma unroll
    for (int j = 0; j < GBINS / 256; j++) {
        lh[tid + j * 256] = 0;
        ls[tid + j * 256] = 0.0f;
    }
    __syncthreads();

    float pos_acc = 0.0f;
    for (int i = tid; i < NPRIOR; i += 256) {
        size_t o = (size_t)b * NPRIOR + i;
        float lse = lse_g[o];
        int tgt = conf_t[o];
        float mv;
        if (tgt > 0) {
            mv = 0.0f;
            pos_acc += lse - conf_data[o * NC + tgt];
        } else {
            mv = fmaxf(lse - c0_g[o], 0.0f);
        }
        int bin = min((int)(mv * 128.0f), GBINS - 1);
        atomicAdd(&lh[bin], 1);
        atomicAdd(&ls[bin], mv);
    }

    int np = np_fix[b];
#pragma unroll
    for (int c = 0; c < MSPLIT; c++) np += np_part[b * MSPLIT + c];
    const int kk = min(max(3 * np, 1), NPRIOR - 1);
    __syncthreads();

    int   cnt[8];
    float sm[8];
#pragma unroll
    for (int j = 0; j < 8; j++) { cnt[j] = lh[tid * 8 + j]; sm[j] = ls[tid * 8 + j]; }
    int own = 0;
#pragma unroll
    for (int j = 0; j < 8; j++) own += cnt[j];

    int incl = own;
#pragma unroll
    for (int off = 1; off < 64; off <<= 1) {
        int t = __shfl_down(incl, off);
        incl += (lane + off < 64) ? t : 0;
    }
    if (lane == 0) wtot[wave] = incl;
    __syncthreads();
    int hi = 0;
#pragma unroll
    for (int w = 0; w < 4; w++) if (w > wave) hi += wtot[w];
    const int suf = (incl - own) + hi;

    int found = -1;                         // pack: B0*16384 + r
    int s2 = suf;
#pragma unroll
    for (int j = 7; j >= 0; j--) {
        if (found < 0 && s2 < kk && kk <= s2 + cnt[j])
            found = (tid * 8 + j) * 16384 + (kk - s2);
        s2 += cnt[j];
    }
    if (found >= 0) { s_B0 = found >> 14; s_r = found & 16383; }
    __syncthreads();
    const int B0 = s_B0;
    const int r  = s_r;

    float sg = 0.0f;
#pragma unroll
    for (int j = 0; j < 8; j++) {
        int bin = tid * 8 + j;
        if (bin > B0)       sg += sm[j];
        else if (bin == B0) sg += (float)r * (sm[j] / (float)cnt[j]);
    }
    for (int off = 32; off; off >>= 1) {
        sg += __shfl_xor(sg, off);
        pos_acc += __shfl_xor(pos_acc, off);
    }
    if (lane == 0) { red_f[wave] = sg; red_p[wave] = pos_acc; }
    __syncthreads();
    if (tid == 0) {
        lc2[b] = red_f[0] + red_f[1] + red_f[2] + red_f[3];
        lc3[b] = red_p[0] + red_p[1] + red_p[2] + red_p[3];
    }
}

// ---------------------------------------------------------------- k_final
__global__ __launch_bounds__(1024) void k_final(
    const float* __restrict__ lc2, const float* __restrict__ lc3,
    const float* __restrict__ ll_part, const int* __restrict__ np_part,
    const float* __restrict__ ll_fix, const int* __restrict__ np_fix,
    float* __restrict__ out)
{
    __shared__ float rf[16][2];
    __shared__ int   rn[16];
    const int tid = threadIdx.x;
    float lc = 0.0f, ll = 0.0f;
    int np = 0;
    if (tid < BATCH) { lc = lc2[tid] + lc3[tid]; ll += ll_fix[tid]; np += np_fix[tid]; }
    if (tid < BATCH * MSPLIT) { ll += ll_part[tid]; np += np_part[tid]; }
    for (int off = 32; off; off >>= 1) {
        lc += __shfl_xor(lc, off);
        ll += __shfl_xor(ll, off);
        np += __shfl_xor(np, off);
    }
    const int lane = tid & 63, wave = tid >> 6;
    if (lane == 0) { rf[wave][0] = lc; rf[wave][1] = ll; rn[wave] = np; }
    __syncthreads();
    if (tid == 0) {
        float lcT = 0.0f, llT = 0.0f; int npT = 0;
        for (int w = 0; w < 16; w++) { lcT += rf[w][0]; llT += rf[w][1]; npT += rn[w]; }
        float N = fmaxf((float)npT, 1.0f);
        out[0] = llT / N;
        out[1] = lcT / N;
    }
}

// ---------------------------------------------------------------- launch
// 4 nodes: fused(match || lse) -> bpi_fix -> histsel2 -> final.
extern "C" void kernel_launch(void* const* d_in, const int* in_sizes, int n_in,
                              void* d_out, int out_size, void* d_ws, size_t ws_size,
                              hipStream_t stream)
{
    const float* loc_data  = (const float*)d_in[0];
    const float* conf_data = (const float*)d_in[1];
    const float* gt_boxes  = (const float*)d_in[2];
    const int*   gt_labels = (const int*)d_in[3];
    const float* priors    = (const float*)d_in[4];
    float* out = (float*)d_out;

    char* ws = (char*)d_ws;
    float* ll_part  = (float*)(ws + 0);                          // 1024 floats
    int*   np_part  = (int*)(ws + 4096);                         // 1024 ints
    float* lc2      = (float*)(ws + 8192);                       // 64 floats
    float* lc3      = (float*)(ws + 8448);                       // 64 floats
    float* ll_fix   = (float*)(ws + 8704);                       // 64 floats
    int*   np_fix   = (int*)(ws + 9216);                         // 64 ints
    int*   conf_t   = (int*)(ws + 65536);                        // 2.24 MB
    float* lse_g    = (float*)(ws + 65536 + 2235392);            // 2.24 MB
    float* c0_g     = (float*)(ws + 65536 + 2 * 2235392);        // 2.24 MB
    float* candv    = (float*)(ws + 8388608);                    // 64 KB
    int*   candi    = (int*)(ws + 8454144);                      // 64 KB

    hipLaunchKernelGGL(k_fused, dim3(2560), dim3(256), 0, stream,
                       loc_data, gt_boxes, gt_labels, priors, conf_data,
                       conf_t, ll_part, np_part, candv, candi, lse_g, c0_g);
    hipLaunchKernelGGL(k_bpi_fix, dim3(BATCH), dim3(64), 0, stream,
                       loc_data, gt_boxes, gt_labels, priors, candv, candi,
                       conf_t, ll_fix, np_fix);
    hipLaunchKernelGGL(k_histsel2, dim3(BATCH), dim3(256), 0, stream,
                       conf_data, lse_g, c0_g, conf_t, np_part, np_fix,
                       lc2, lc3);
    hipLaunchKernelGGL(k_final, dim3(1), dim3(1024), 0, stream,
                       lc2, lc3, ll_part, np_part, ll_fix, np_fix, out);
}

// Round 27
// 101.012 us; speedup vs baseline: 1.1608x; 1.1608x over previous
//
#include <hip/hip_runtime.h>
#include <math.h>

#define BATCH 64
#define NOBJ 16
#define NPRIOR 8732
#define NC 91
#define IMG 300.0f
#define GPB 1092                   // 8-row groups per batch (k_ce)
#define NGROUP (GPB * BATCH)       // 69888
#define CE_GRID 6144               // one-wave blocks
#define GBINS 2048                 // histogram bins: bin = min(2047, v*128)
#define MSPLIT 16                  // match blocks per batch
#define SL 546                     // priors per match slice (16*546 >= 8732)

// ---------------------------------------------------------------- k_match1
// FUSED match (R25-verified best): IoU -> conf_t (pre-override) -> loc-loss
// partials -> bpi candidates; matched-box coords fetched post-loop via
// runtime-indexed LDS (exact).
__global__ __launch_bounds__(256) void k_match1(
    const float* __restrict__ loc_data,
    const float* __restrict__ gt_boxes,
    const int*   __restrict__ gt_labels,
    const float* __restrict__ priors,
    int*   __restrict__ conf_t,
    float* __restrict__ ll_part,           // [B*MSPLIT]
    int*   __restrict__ np_part,           // [B*MSPLIT]
    float* __restrict__ candv,             // [B][MSPLIT][NOBJ]
    int*   __restrict__ candi)             // [B][MSPLIT][NOBJ]
{
    __shared__ float bx0[NOBJ], by0[NOBJ], bx1[NOBJ], by1[NOBJ], barea[NOBJ];
    __shared__ int   blab[NOBJ];
    __shared__ float rv[NOBJ][4];
    __shared__ int   ri[NOBJ][4];
    __shared__ float red_f[4];
    __shared__ int   red_i[4];

    const int b    = blockIdx.y;
    const int blk  = blockIdx.x;
    const int tid  = threadIdx.x;
    const int lane = tid & 63;
    const int wave = tid >> 6;             // 0..3
    const int p0   = blk * SL;
    const int pend = min(p0 + SL, NPRIOR);

    if (tid < NOBJ) {
        float4 g = ((const float4*)gt_boxes)[(size_t)b * NOBJ + tid];
        float x0 = g.x * (1.0f / IMG), y0 = g.y * (1.0f / IMG);
        float x1 = g.z * (1.0f / IMG), y1 = g.w * (1.0f / IMG);
        bx0[tid] = x0; by0[tid] = y0; bx1[tid] = x1; by1[tid] = y1;
        barea[tid] = (x1 - x0) * (y1 - y0);
        blab[tid] = gt_labels[b * NOBJ + tid];
    }
    __syncthreads();

    float bv[NOBJ];
    int   bi[NOBJ];
#pragma unroll
    for (int j = 0; j < NOBJ; j++) { bv[j] = -1.0f; bi[j] = 0x7fffffff; }

    int np_local = 0;
    float ll_local = 0.0f;

    for (int p = p0 + tid; p < pend; p += 256) {
        float4 pr = ((const float4*)priors)[p];
        float cx = pr.x, cy = pr.y, w = pr.z, h = pr.w;
        float px0 = cx - 0.5f * w, py0 = cy - 0.5f * h;
        float px1 = cx + 0.5f * w, py1 = cy + 0.5f * h;
        float pa = w * h;
        float maxv = -1.0f; int maxj = 0;
#pragma unroll
        for (int j = 0; j < NOBJ; j++) {
            float ltx = fmaxf(bx0[j], px0), lty = fmaxf(by0[j], py0);
            float rbx = fminf(bx1[j], px1), rby = fminf(by1[j], py1);
            float iw = fmaxf(rbx - ltx, 0.0f), ih = fmaxf(rby - lty, 0.0f);
            float inter = iw * ih;
            float iou = inter / (barea[j] + pa - inter);
            if (iou > maxv) { maxv = iou; maxj = j; }        // first argmax over j
            if (iou > bv[j]) { bv[j] = iou; bi[j] = p; }     // first argmax over p
        }
        int conf = (maxv < 0.5f) ? 0 : blab[maxj];
        conf_t[(size_t)b * NPRIOR + p] = conf;
        if (conf > 0) {
            np_local++;
            float mx0 = bx0[maxj], my0 = by0[maxj];
            float mx1 = bx1[maxj], my1 = by1[maxj];
            float g0 = ((mx0 + mx1) * 0.5f - cx) / (0.1f * w);
            float g1 = ((my0 + my1) * 0.5f - cy) / (0.1f * h);
            float g2 = logf((mx1 - mx0) / w) * 5.0f;
            float g3 = logf((my1 - my0) / h) * 5.0f;
            float4 lv = ((const float4*)loc_data)[(size_t)b * NPRIOR + p];
            float d0 = lv.x - g0, d1 = lv.y - g1, d2 = lv.z - g2, d3 = lv.w - g3;
            float a0 = fabsf(d0), a1 = fabsf(d1), a2 = fabsf(d2), a3 = fabsf(d3);
            ll_local += (a0 < 1.f ? 0.5f * d0 * d0 : a0 - 0.5f)
                      + (a1 < 1.f ? 0.5f * d1 * d1 : a1 - 0.5f)
                      + (a2 < 1.f ? 0.5f * d2 * d2 : a2 - 0.5f)
                      + (a3 < 1.f ? 0.5f * d3 * d3 : a3 - 0.5f);
        }
    }

    // per-j block-best candidates (tie: smaller p; lanes hold ascending p)
#pragma unroll
    for (int j = 0; j < NOBJ; j++) {
        float v = bv[j]; int ix = bi[j];
        for (int off = 32; off; off >>= 1) {
            float v2 = __shfl_xor(v, off);
            int   i2 = __shfl_xor(ix, off);
            if (v2 > v || (v2 == v && i2 < ix)) { v = v2; ix = i2; }
        }
        if (lane == 0) { rv[j][wave] = v; ri[j][wave] = ix; }
    }
    for (int off = 32; off; off >>= 1) {
        ll_local += __shfl_xor(ll_local, off);
        np_local += __shfl_xor(np_local, off);
    }
    if (lane == 0) { red_f[wave] = ll_local; red_i[wave] = np_local; }
    __syncthreads();
    if (tid < NOBJ) {
        int j = tid;
        float v = rv[j][0]; int ix = ri[j][0];
#pragma unroll
        for (int w2 = 1; w2 < 4; w2++) {
            float v2 = rv[j][w2]; int i2 = ri[j][w2];
            if (v2 > v || (v2 == v && i2 < ix)) { v = v2; ix = i2; }
        }
        size_t o = ((size_t)b * MSPLIT + blk) * NOBJ + j;
        candv[o] = v;
        candi[o] = ix;
    }
    if (tid == 0) {
        ll_part[b * MSPLIT + blk] = red_f[0] + red_f[1] + red_f[2] + red_f[3];
        np_part[b * MSPLIT + blk] = red_i[0] + red_i[1] + red_i[2] + red_i[3];
    }
}

// ---------------------------------------------------------------- k_bpi_fix
// MERGED bpi + fix: one wave per batch. Lanes 0-15 reduce the MSPLIT
// candidate copies -> bpi (ascending order preserves smaller-index
// tie-break), then apply the override to <=16 priors with EXACT ll/np
// deltas (byte-identical arithmetic; last j wins = in-order scatter).
__global__ __launch_bounds__(64) void k_bpi_fix(
    const float* __restrict__ loc_data,
    const float* __restrict__ gt_boxes,
    const int*   __restrict__ gt_labels,
    const float* __restrict__ priors,
    const float* __restrict__ candv,
    const int*   __restrict__ candi,
    int*   __restrict__ conf_t,
    float* __restrict__ ll_fix,            // [B]
    int*   __restrict__ np_fix)            // [B]
{
    __shared__ int bpi_s[NOBJ];
    const int b = blockIdx.x;
    const int lane = threadIdx.x;

    if (lane < NOBJ) {
        size_t base = (size_t)b * MSPLIT * NOBJ + lane;
        float v = candv[base]; int ix = candi[base];
#pragma unroll
        for (int c = 1; c < MSPLIT; c++) {
            float v2 = candv[base + c * NOBJ];
            int   i2 = candi[base + c * NOBJ];
            if (v2 > v || (v2 == v && i2 < ix)) { v = v2; ix = i2; }
        }
        bpi_s[lane] = ix;
    }
    __syncthreads();

    float ll_d = 0.0f;
    int   np_d = 0;

    if (lane < NOBJ) {
        const int j = lane;
        const int ps = bpi_s[j];
        bool last = true;
        for (int j2 = j + 1; j2 < NOBJ; j2++)
            if (bpi_s[j2] == ps) last = false;
        if (last) {
            float4 pr = ((const float4*)priors)[ps];
            float cx = pr.x, cy = pr.y, w = pr.z, h = pr.w;
            float px0 = cx - 0.5f * w, py0 = cy - 0.5f * h;
            float px1 = cx + 0.5f * w, py1 = cy + 0.5f * h;
            float pa = w * h;
            float maxv = -1.0f;
            float mx0 = 0, my0 = 0, mx1 = 0, my1 = 0;
            float jx0 = 0, jy0 = 0, jx1 = 0, jy1 = 0;
            for (int j2 = 0; j2 < NOBJ; j2++) {
                float4 g = ((const float4*)gt_boxes)[(size_t)b * NOBJ + j2];
                float x0 = g.x * (1.0f / IMG), y0 = g.y * (1.0f / IMG);
                float x1 = g.z * (1.0f / IMG), y1 = g.w * (1.0f / IMG);
                float area = (x1 - x0) * (y1 - y0);
                float ltx = fmaxf(x0, px0), lty = fmaxf(y0, py0);
                float rbx = fminf(x1, px1), rby = fminf(y1, py1);
                float iw = fmaxf(rbx - ltx, 0.0f), ih = fmaxf(rby - lty, 0.0f);
                float inter = iw * ih;
                float iou = inter / (area + pa - inter);
                if (iou > maxv) { maxv = iou; mx0 = x0; my0 = y0; mx1 = x1; my1 = y1; }
                if (j2 == j)    { jx0 = x0; jy0 = y0; jx1 = x1; jy1 = y1; }
            }
            float4 lv = ((const float4*)loc_data)[(size_t)b * NPRIOR + ps];
            if (maxv >= 0.5f) {           // old contribution (labels >= 1)
                float g0 = ((mx0 + mx1) * 0.5f - cx) / (0.1f * w);
                float g1 = ((my0 + my1) * 0.5f - cy) / (0.1f * h);
                float g2 = logf((mx1 - mx0) / w) * 5.0f;
                float g3 = logf((my1 - my0) / h) * 5.0f;
                float d0 = lv.x - g0, d1 = lv.y - g1, d2 = lv.z - g2, d3 = lv.w - g3;
                float a0 = fabsf(d0), a1 = fabsf(d1), a2 = fabsf(d2), a3 = fabsf(d3);
                ll_d -= (a0 < 1.f ? 0.5f * d0 * d0 : a0 - 0.5f)
                      + (a1 < 1.f ? 0.5f * d1 * d1 : a1 - 0.5f)
                      + (a2 < 1.f ? 0.5f * d2 * d2 : a2 - 0.5f)
                      + (a3 < 1.f ? 0.5f * d3 * d3 : a3 - 0.5f);
                np_d -= 1;
            }
            {                              // new contribution (box j)
                float g0 = ((jx0 + jx1) * 0.5f - cx) / (0.1f * w);
                float g1 = ((jy0 + jy1) * 0.5f - cy) / (0.1f * h);
                float g2 = logf((jx1 - jx0) / w) * 5.0f;
                float g3 = logf((jy1 - jy0) / h) * 5.0f;
                float d0 = lv.x - g0, d1 = lv.y - g1, d2 = lv.z - g2, d3 = lv.w - g3;
                float a0 = fabsf(d0), a1 = fabsf(d1), a2 = fabsf(d2), a3 = fabsf(d3);
                ll_d += (a0 < 1.f ? 0.5f * d0 * d0 : a0 - 0.5f)
                      + (a1 < 1.f ? 0.5f * d1 * d1 : a1 - 0.5f)
                      + (a2 < 1.f ? 0.5f * d2 * d2 : a2 - 0.5f)
                      + (a3 < 1.f ? 0.5f * d3 * d3 : a3 - 0.5f);
                np_d += 1;
            }
            conf_t[(size_t)b * NPRIOR + ps] = gt_labels[b * NOBJ + j];
        }
    }

    for (int off = 32; off; off >>= 1) {
        ll_d += __shfl_xor(ll_d, off);
        np_d += __shfl_xor(np_d, off);
    }
    if (lane == 0) { ll_fix[b] = ll_d; np_fix[b] = np_d; }
}

// ---------------------------------------------------------------- k_ce
#define CE_ISSUE(gg, R0, R1, R2, NF)                                           \
    {   int b_ = (gg) / GPB, ci_ = (gg) - b_ * GPB;                            \
        int p0_ = ci_ * 8;                                                     \
        int rows_ = min(8, NPRIOR - p0_);                                      \
        NF = (rows_ * NC) >> 2;                                                \
        const float4* s_ = (const float4*)(conf_data + ((size_t)b_ * NPRIOR + p0_) * NC); \
        R0 = s_[tid];                                                          \
        if (tid + 64  < NF) R1 = s_[tid + 64];                                 \
        if (tid + 128 < NF) R2 = s_[tid + 128]; }

#define CT_LOAD(gg)                                                            \
    ( conf_t[(size_t)((gg) / GPB) * NPRIOR + ((gg) - ((gg) / GPB) * GPB) * 8 + (tid >> 3)] )

#define CE_WRITE(BUF, R0, R1, R2, NF)                                          \
    {   float4* d_ = (float4*)sbuf[BUF];                                       \
        d_[tid] = R0;                                                          \
        if (tid + 64  < NF) d_[tid + 64]  = R1;                                \
        if (tid + 128 < NF) d_[tid + 128] = R2; }

#define CE_COMPUTE(gg, BUF, TG)                                                \
    {   int b_ = (gg) / GPB, ci_ = (gg) - b_ * GPB;                            \
        int p0_ = ci_ * 8;                                                     \
        int rows_ = min(8, NPRIOR - p0_);                                      \
        int rr_ = tid >> 3, q_ = tid & 7;                                      \
        if (rr_ < rows_) {                                                     \
            const float* row_ = sbuf[BUF] + rr_ * NC;                          \
            float s_ = 0.0f;                                                   \
            _Pragma("unroll")                                                  \
            for (int i_ = q_; i_ < NC; i_ += 8) s_ += __expf(row_[i_]);        \
            s_ += __shfl_xor(s_, 1);                                           \
            s_ += __shfl_xor(s_, 2);                                           \
            s_ += __shfl_xor(s_, 4);                                           \
            if (q_ == 0) {                                                     \
                size_t o_ = (size_t)b_ * NPRIOR + p0_ + rr_;                   \
                int tgt_ = TG;                                                 \
                float ce_ = __logf(s_) - row_[tgt_];                           \
                if (tgt_ > 0) { pos_acc += ce_; mine[o_] = 0.0f; }             \
                else          { mine[o_] = fmaxf(ce_, 0.0f); }                 \
            } } }

__global__ __launch_bounds__(64) void k_ce(
    const float* __restrict__ conf_data,
    const int*   __restrict__ conf_t,
    float* __restrict__ mine,
    float* __restrict__ lc_part)
{
    __shared__ float sbuf[2][8 * NC];
    const int tid = threadIdx.x;
    const int G = CE_GRID;

    float4 a0, a1, a2, b0, b1, b2;
    int nfA = 0, nfB = 0;
    float pos_acc = 0.0f;

    int g = blockIdx.x;
    CE_ISSUE(g, a0, a1, a2, nfA);
    int tcur = CT_LOAD(g);
    if (g + G < NGROUP) CE_ISSUE(g + G, b0, b1, b2, nfB);
    CE_WRITE(0, a0, a1, a2, nfA);

    for (; g < NGROUP; g += 2 * G) {
        int tnext = (g + G < NGROUP) ? CT_LOAD(g + G) : 0;
        if (g + 2 * G < NGROUP) CE_ISSUE(g + 2 * G, a0, a1, a2, nfA);
        CE_COMPUTE(g, 0, tcur);
        if (g + G < NGROUP) {
            CE_WRITE(1, b0, b1, b2, nfB);
            int tn2 = (g + 2 * G < NGROUP) ? CT_LOAD(g + 2 * G) : 0;
            if (g + 3 * G < NGROUP) CE_ISSUE(g + 3 * G, b0, b1, b2, nfB);
            CE_COMPUTE(g + G, 1, tnext);
            if (g + 2 * G < NGROUP) CE_WRITE(0, a0, a1, a2, nfA);
            tcur = tn2;
        }
    }

    for (int off = 32; off; off >>= 1) pos_acc += __shfl_xor(pos_acc, off);
    if (tid == 0) lc_part[blockIdx.x] = pos_acc;
}

// ---------------------------------------------------------------- k_histsel
// MERGED hist + sel: one block (256 thr) per batch; LDS histogram + 8-bins/
// thread suffix-scan + bin-mean top-k approximation (R16-verified).
__global__ __launch_bounds__(256) void k_histsel(
    const float* __restrict__ mine,
    const int*   __restrict__ np_part,
    const int*   __restrict__ np_fix,
    float* __restrict__ lc2)               // [B]
{
    __shared__ int   lh[GBINS];            // 8 KB
    __shared__ float ls[GBINS];            // 8 KB
    __shared__ int   wtot[4];
    __shared__ int   s_B0, s_r;
    __shared__ float red_f[4];

    const int b = blockIdx.x;
    const int tid = threadIdx.x;
    const int lane = tid & 63;
    const int wave = tid >> 6;

#pragma unroll
    for (int j = 0; j < GBINS / 256; j++) {
        lh[tid + j * 256] = 0;
        ls[tid + j * 256] = 0.0f;
    }
    __syncthreads();

    for (int i = tid; i < NPRIOR; i += 256) {
        float v = mine[(size_t)b * NPRIOR + i];
        int bin = min((int)(v * 128.0f), GBINS - 1);
        atomicAdd(&lh[bin], 1);
        atomicAdd(&ls[bin], v);
    }

    int np = np_fix[b];
#pragma unroll
    for (int c = 0; c < MSPLIT; c++) np += np_part[b * MSPLIT + c];
    const int kk = min(max(3 * np, 1), NPRIOR - 1);
    __syncthreads();

    int   cnt[8];
    float sm[8];
#pragma unroll
    for (int j = 0; j < 8; j++) { cnt[j] = lh[tid * 8 + j]; sm[j] = ls[tid * 8 + j]; }
    int own = 0;
#pragma unroll
    for (int j = 0; j < 8; j++) own += cnt[j];

    int incl = own;
#pragma unroll
    for (int off = 1; off < 64; off <<= 1) {
        int t = __shfl_down(incl, off);
        incl += (lane + off < 64) ? t : 0;
    }
    if (lane == 0) wtot[wave] = incl;
    __syncthreads();
    int hi = 0;
#pragma unroll
    for (int w = 0; w < 4; w++) if (w > wave) hi += wtot[w];
    const int suf = (incl - own) + hi;

    int found = -1;                         // pack: B0*16384 + r
    int s2 = suf;
#pragma unroll
    for (int j = 7; j >= 0; j--) {
        if (found < 0 && s2 < kk && kk <= s2 + cnt[j])
            found = (tid * 8 + j) * 16384 + (kk - s2);
        s2 += cnt[j];
    }
    if (found >= 0) { s_B0 = found >> 14; s_r = found & 16383; }
    __syncthreads();
    const int B0 = s_B0;
    const int r  = s_r;

    float sg = 0.0f;
#pragma unroll
    for (int j = 0; j < 8; j++) {
        int bin = tid * 8 + j;
        if (bin > B0)       sg += sm[j];
        else if (bin == B0) sg += (float)r * (sm[j] / (float)cnt[j]);
    }
    for (int off = 32; off; off >>= 1) sg += __shfl_xor(sg, off);
    if (lane == 0) red_f[wave] = sg;
    __syncthreads();
    if (tid == 0) lc2[b] = red_f[0] + red_f[1] + red_f[2] + red_f[3];
}

// ---------------------------------------------------------------- k_final
__global__ __launch_bounds__(1024) void k_final(
    const float* __restrict__ lc_part, const float* __restrict__ lc2,
    const float* __restrict__ ll_part, const int* __restrict__ np_part,
    const float* __restrict__ ll_fix, const int* __restrict__ np_fix,
    float* __restrict__ out)
{
    __shared__ float rf[16][2];
    __shared__ int   rn[16];
    const int tid = threadIdx.x;
    float lc = 0.0f;
    for (int i = tid; i < CE_GRID; i += 1024) lc += lc_part[i];
    float ll = 0.0f; int np = 0;
    if (tid < BATCH) { lc += lc2[tid]; ll += ll_fix[tid]; np += np_fix[tid]; }
    if (tid < BATCH * MSPLIT) { ll += ll_part[tid]; np += np_part[tid]; }
    for (int off = 32; off; off >>= 1) {
        lc += __shfl_xor(lc, off);
        ll += __shfl_xor(ll, off);
        np += __shfl_xor(np, off);
    }
    const int lane = tid & 63, wave = tid >> 6;
    if (lane == 0) { rf[wave][0] = lc; rf[wave][1] = ll; rn[wave] = np; }
    __syncthreads();
    if (tid == 0) {
        float lcT = 0.0f, llT = 0.0f; int npT = 0;
        for (int w = 0; w < 16; w++) { lcT += rf[w][0]; llT += rf[w][1]; npT += rn[w]; }
        float N = fmaxf((float)npT, 1.0f);
        out[0] = llT / N;
        out[1] = lcT / N;
    }
}

// ---------------------------------------------------------------- launch
extern "C" void kernel_launch(void* const* d_in, const int* in_sizes, int n_in,
                              void* d_out, int out_size, void* d_ws, size_t ws_size,
                              hipStream_t stream)
{
    const float* loc_data  = (const float*)d_in[0];
    const float* conf_data = (const float*)d_in[1];
    const float* gt_boxes  = (const float*)d_in[2];
    const int*   gt_labels = (const int*)d_in[3];
    const float* priors    = (const float*)d_in[4];
    float* out = (float*)d_out;

    char* ws = (char*)d_ws;
    float* ll_part  = (float*)(ws + 0);                          // 1024 floats
    int*   np_part  = (int*)(ws + 4096);                         // 1024 ints
    float* lc2      = (float*)(ws + 8192);                       // 64 floats
    float* ll_fix   = (float*)(ws + 8704);                       // 64 floats
    int*   np_fix   = (int*)(ws + 9216);                         // 64 ints
    float* lc_part  = (float*)(ws + 12288);                      // 6144 floats
    int*   conf_t   = (int*)(ws + 65536);                        // 2.24 MB
    float* mine     = (float*)(ws + 65536 + 2235392);            // 2.24 MB
    float* candv    = (float*)(ws + 7340032);                    // 64 KB
    int*   candi    = (int*)(ws + 7405568);                      // 64 KB

    hipLaunchKernelGGL(k_match1, dim3(MSPLIT, BATCH), dim3(256), 0, stream,
                       loc_data, gt_boxes, gt_labels, priors,
                       conf_t, ll_part, np_part, candv, candi);
    hipLaunchKernelGGL(k_bpi_fix, dim3(BATCH), dim3(64), 0, stream,
                       loc_data, gt_boxes, gt_labels, priors, candv, candi,
                       conf_t, ll_fix, np_fix);
    hipLaunchKernelGGL(k_ce, dim3(CE_GRID), dim3(64), 0, stream,
                       conf_data, conf_t, mine, lc_part);
    hipLaunchKernelGGL(k_histsel, dim3(BATCH), dim3(256), 0, stream,
                       mine, np_part, np_fix, lc2);
    hipLaunchKernelGGL(k_final, dim3(1), dim3(1024), 0, stream,
                       lc_part, lc2, ll_part, np_part, ll_fix, np_fix, out);
}